// Round 1
// baseline (317.197 us; speedup 1.0000x reference)
//
#include <hip/hip_runtime.h>
#include <math.h>

#define NLEV 5
#define TOPKK 1000
#define NCLS 16
#define CAND_CAP 2048
#define NTOT 785664u

// level boundaries (flat index over concatenated levels)
// sizes: 589824, 147456, 36864, 9216, 2304
__device__ __forceinline__ int find_level(unsigned i, unsigned& loc) {
    if (i < 589824u) { loc = i;            return 0; }
    if (i < 737280u) { loc = i - 589824u;  return 1; }
    if (i < 774144u) { loc = i - 737280u;  return 2; }
    if (i < 783360u) { loc = i - 774144u;  return 3; }
    loc = i - 783360u; return 4;
}

struct Ptrs {
    const float* anc[NLEV];
    const float* cls[NLEV];
    const float* reg[NLEV];
};

// order-preserving float32 -> uint32 (larger uint == larger float)
__device__ __forceinline__ unsigned f2key(float f) {
    unsigned u = __float_as_uint(f);
    return (u & 0x80000000u) ? ~u : (u | 0x80000000u);
}

__global__ void k_init(unsigned* hist, unsigned* prefix, unsigned* remaining, unsigned* cnt) {
    int t = blockIdx.x * blockDim.x + threadIdx.x;
    for (int i = t; i < NLEV * 256; i += blockDim.x * gridDim.x) hist[i] = 0u;
    if (t < NLEV) { prefix[t] = 0u; remaining[t] = TOPKK; cnt[t] = 0u; }
}

__global__ void k_keys(Ptrs p, unsigned* keys) {
    unsigned i = blockIdx.x * blockDim.x + threadIdx.x;
    if (i >= NTOT) return;
    unsigned loc; int l = find_level(i, loc);
    const float4* c = (const float4*)(p.cls[l]) + (size_t)loc * 4;
    float4 a = c[0], b = c[1], d = c[2], e = c[3];
    float m = fmaxf(fmaxf(fmaxf(a.x, a.y), fmaxf(a.z, a.w)),
                    fmaxf(fmaxf(fmaxf(b.x, b.y), fmaxf(b.z, b.w)),
                          fmaxf(fmaxf(fmaxf(d.x, d.y), fmaxf(d.z, d.w)),
                                fmaxf(fmaxf(e.x, e.y), fmaxf(e.z, e.w)))));
    keys[i] = f2key(m);
}

__global__ void k_hist(const unsigned* keys, const unsigned* prefix, unsigned* hist,
                       unsigned maskhi, int shift) {
    __shared__ unsigned lh[NLEV * 256];
    __shared__ unsigned pf[NLEV];
    for (int t = threadIdx.x; t < NLEV * 256; t += blockDim.x) lh[t] = 0u;
    if (threadIdx.x < NLEV) pf[threadIdx.x] = prefix[threadIdx.x] & maskhi;
    __syncthreads();
    unsigned i = blockIdx.x * blockDim.x + threadIdx.x;
    if (i < NTOT) {
        unsigned loc; int l = find_level(i, loc);
        unsigned k = keys[i];
        if ((k & maskhi) == pf[l])
            atomicAdd(&lh[l * 256 + ((k >> shift) & 0xFFu)], 1u);
    }
    __syncthreads();
    for (int t = threadIdx.x; t < NLEV * 256; t += blockDim.x)
        if (lh[t]) atomicAdd(&hist[t], lh[t]);
}

// one block, 256 threads: per level find the radix bucket holding the k-th
// largest, update prefix/remaining, zero hist for next pass
__global__ void k_select(unsigned* hist, unsigned* prefix, unsigned* remaining, int shift) {
    __shared__ unsigned s[256];
    int t = threadIdx.x;            // t == bin
    int r = 255 - t;                // reversed index: prefix-sum over r == suffix over bin
    for (int l = 0; l < NLEV; l++) {
        unsigned c = hist[l * 256 + t];
        hist[l * 256 + t] = 0u;     // ready for next pass
        s[r] = c;
        __syncthreads();
        // Hillis-Steele inclusive scan over s[0..255]
        for (int d = 1; d < 256; d <<= 1) {
            unsigned v = (r >= d) ? s[r - d] : 0u;
            __syncthreads();
            s[r] += v;
            __syncthreads();
        }
        unsigned incl = s[r];
        unsigned above = incl - c;       // count of keys in strictly higher bins
        unsigned rem = remaining[l];
        __syncthreads();                 // all reads of remaining[l] done before write
        if (above < rem && rem <= incl) {
            prefix[l] |= ((unsigned)t) << shift;
            remaining[l] = rem - above;
        }
        __syncthreads();
    }
}

__global__ void k_compact(const unsigned* keys, const unsigned* prefix,
                          unsigned* cnt, unsigned long long* cand) {
    unsigned i = blockIdx.x * blockDim.x + threadIdx.x;
    if (i >= NTOT) return;
    unsigned loc; int l = find_level(i, loc);
    unsigned k = keys[i];
    unsigned T = prefix[l];
    if (k >= T) {
        unsigned slot = atomicAdd(&cnt[l], 1u);
        if (slot < CAND_CAP)
            cand[(size_t)l * CAND_CAP + slot] =
                ((unsigned long long)k << 32) | (unsigned)(~loc);
    }
}

__global__ __launch_bounds__(1024) void k_sort_emit(Ptrs p, const unsigned* cnt,
                                                    const unsigned long long* cand,
                                                    float* out) {
    const float MAXD = 4.135166556742356f;   // log(1000/16)
    int l = blockIdx.x;
    int t = threadIdx.x;
    __shared__ unsigned long long buf[CAND_CAP];
    __shared__ float4 sbox[TOPKK];
    __shared__ unsigned sidx[TOPKK];

    unsigned n = cnt[l];
    if (n > CAND_CAP) n = CAND_CAP;
    for (int i = t; i < CAND_CAP; i += 1024)
        buf[i] = (i < (int)n) ? cand[(size_t)l * CAND_CAP + i] : 0ULL;
    __syncthreads();

    // bitonic sort, descending (composite: key desc, then index asc)
    for (unsigned k = 2; k <= CAND_CAP; k <<= 1) {
        for (unsigned j = k >> 1; j > 0; j >>= 1) {
            for (unsigned i = t; i < CAND_CAP; i += 1024) {
                unsigned x = i ^ j;
                if (x > i) {
                    unsigned long long a = buf[i], b = buf[x];
                    bool desc = ((i & k) == 0);
                    if (desc ? (a < b) : (a > b)) { buf[i] = b; buf[x] = a; }
                }
            }
            __syncthreads();
        }
    }

    // decode boxes for the 1000 winners
    if (t < TOPKK) {
        unsigned idx = ~((unsigned)(buf[t] & 0xFFFFFFFFull));
        sidx[t] = idx;
        float4 a = ((const float4*)p.anc[l])[idx];
        float4 d = ((const float4*)p.reg[l])[(size_t)idx * 2];   // first 4 of 8
        float w = a.z - a.x, h = a.w - a.y;
        float cx = a.x + 0.5f * w, cy = a.y + 0.5f * h;
        float pcx = cx + d.x * w, pcy = cy + d.y * h;
        float pw = w * expf(fminf(d.z, MAXD));
        float ph = h * expf(fminf(d.w, MAXD));
        sbox[t] = make_float4(pcx - 0.5f * pw, pcy - 0.5f * ph,
                              pcx + 0.5f * pw, pcy + 0.5f * ph);
    }
    __syncthreads();

    const float* cp = p.cls[l];
    for (int o = t; o < TOPKK * NCLS; o += 1024) {
        int j = o >> 4, c = o & 15;
        float sc = cp[(size_t)sidx[j] * NCLS + c];
        sc = 1.0f / (1.0f + expf(-sc));
        float4 b = sbox[j];
        float* q = out + (size_t)((l * TOPKK + j) * NCLS + c) * 6;
        q[0] = b.x; q[1] = b.y; q[2] = b.z; q[3] = b.w;
        q[4] = sc;  q[5] = (float)(c + 1);
    }
}

extern "C" void kernel_launch(void* const* d_in, const int* in_sizes, int n_in,
                              void* d_out, int out_size, void* d_ws, size_t ws_size,
                              hipStream_t stream) {
    Ptrs p;
    for (int l = 0; l < NLEV; l++) {
        p.anc[l] = (const float*)d_in[3 * l + 0];
        p.cls[l] = (const float*)d_in[3 * l + 1];
        p.reg[l] = (const float*)d_in[3 * l + 2];
    }
    char* w = (char*)d_ws;
    unsigned* keys      = (unsigned*)w;                         // 785664 u32
    unsigned* hist      = (unsigned*)(w + 3142656);             // 1280 u32
    unsigned* prefix    = (unsigned*)(w + 3147776);             // 5 u32 (pad to 8)
    unsigned* remaining = prefix + 8;
    unsigned* cnt       = prefix + 16;
    unsigned long long* cand = (unsigned long long*)(w + 3147904); // 5*2048 u64

    float* out = (float*)d_out;
    int nb = (NTOT + 255) / 256;

    k_init<<<8, 256, 0, stream>>>(hist, prefix, remaining, cnt);
    k_keys<<<nb, 256, 0, stream>>>(p, keys);
    k_hist<<<nb, 256, 0, stream>>>(keys, prefix, hist, 0x00000000u, 24);
    k_select<<<1, 256, 0, stream>>>(hist, prefix, remaining, 24);
    k_hist<<<nb, 256, 0, stream>>>(keys, prefix, hist, 0xFF000000u, 16);
    k_select<<<1, 256, 0, stream>>>(hist, prefix, remaining, 16);
    k_hist<<<nb, 256, 0, stream>>>(keys, prefix, hist, 0xFFFF0000u, 8);
    k_select<<<1, 256, 0, stream>>>(hist, prefix, remaining, 8);
    k_hist<<<nb, 256, 0, stream>>>(keys, prefix, hist, 0xFFFFFF00u, 0);
    k_select<<<1, 256, 0, stream>>>(hist, prefix, remaining, 0);
    k_compact<<<nb, 256, 0, stream>>>(keys, prefix, cnt, cand);
    k_sort_emit<<<NLEV, 1024, 0, stream>>>(p, cnt, cand, out);
}

// Round 3
// 227.651 us; speedup vs baseline: 1.3933x; 1.3933x over previous
//
#include <hip/hip_runtime.h>
#include <math.h>

#define NLEV 5
#define TOPKK 1000
#define NCLS 16
#define NPART 16
#define PART_CAP 256
#define CAND_TOT 2048
#define NTOT 785664u
#define HISTSZ (NLEV * 256)

// level boundaries (flat index over concatenated levels)
// sizes: 589824, 147456, 36864, 9216, 2304
__device__ __forceinline__ int find_level(unsigned i, unsigned& loc) {
    if (i < 589824u) { loc = i;            return 0; }
    if (i < 737280u) { loc = i - 589824u;  return 1; }
    if (i < 774144u) { loc = i - 737280u;  return 2; }
    if (i < 783360u) { loc = i - 774144u;  return 3; }
    loc = i - 783360u; return 4;
}

struct Ptrs {
    const float* anc[NLEV];
    const float* cls[NLEV];
    const float* reg[NLEV];
};

// order-preserving float32 -> uint32 (larger uint == larger float)
__device__ __forceinline__ unsigned f2key(float f) {
    unsigned u = __float_as_uint(f);
    return (u & 0x80000000u) ? ~u : (u | 0x80000000u);
}

__device__ __forceinline__ float max4(float4 v) {
    return fmaxf(fmaxf(v.x, v.y), fmaxf(v.z, v.w));
}

// pass over all cls logits: key = sortable(max over 16 classes); build
// 8-bit MSB histogram into NPART partial histograms (cuts same-address
// global-atomic chains 16x)
__global__ void k_keys_hist(Ptrs p, unsigned* keys, unsigned* hist) {
    __shared__ unsigned lh[HISTSZ];
    for (int t = threadIdx.x; t < HISTSZ; t += blockDim.x) lh[t] = 0u;
    __syncthreads();
    unsigned i = blockIdx.x * blockDim.x + threadIdx.x;
    if (i < NTOT) {
        unsigned loc; int l = find_level(i, loc);
        const float4* c = (const float4*)(p.cls[l]) + (size_t)loc * 4;
        float4 a = c[0], b = c[1], d = c[2], e = c[3];
        float m = max4(a);
        m = fmaxf(m, max4(b));
        m = fmaxf(m, max4(d));
        m = fmaxf(m, max4(e));
        unsigned k = f2key(m);
        keys[i] = k;
        atomicAdd(&lh[l * 256 + (k >> 24)], 1u);
    }
    __syncthreads();
    unsigned part = blockIdx.x & (NPART - 1);
    for (int t = threadIdx.x; t < HISTSZ; t += blockDim.x)
        if (lh[t]) atomicAdd(&hist[part * HISTSZ + t], lh[t]);
}

// second radix pass: bits [16:23] of keys whose top byte matches prefix
__global__ void k_hist2(const unsigned* keys, const unsigned* prefix, unsigned* hist) {
    __shared__ unsigned lh[HISTSZ];
    __shared__ unsigned pf[NLEV];
    for (int t = threadIdx.x; t < HISTSZ; t += blockDim.x) lh[t] = 0u;
    if (threadIdx.x < NLEV) pf[threadIdx.x] = prefix[threadIdx.x];
    __syncthreads();
    unsigned i = blockIdx.x * blockDim.x + threadIdx.x;
    if (i < NTOT) {
        unsigned loc; int l = find_level(i, loc);
        unsigned k = keys[i];
        if ((k & 0xFF000000u) == pf[l])
            atomicAdd(&lh[l * 256 + ((k >> 16) & 0xFFu)], 1u);
    }
    __syncthreads();
    unsigned part = blockIdx.x & (NPART - 1);
    for (int t = threadIdx.x; t < HISTSZ; t += blockDim.x)
        if (lh[t]) atomicAdd(&hist[part * HISTSZ + t], lh[t]);
}

// one block, 256 threads: reduce the NPART partial histograms, find the
// radix bucket holding the k-th largest per level, zero partials for reuse
__global__ void k_select(unsigned* hist, unsigned* prefix, unsigned* remaining,
                         int shift, int first) {
    __shared__ unsigned s[256];
    int t = threadIdx.x;            // t == bin
    int r = 255 - t;                // reversed: inclusive scan over r == suffix over bin
    for (int l = 0; l < NLEV; l++) {
        unsigned c = 0;
        for (int pp = 0; pp < NPART; pp++) {
            c += hist[pp * HISTSZ + l * 256 + t];
            hist[pp * HISTSZ + l * 256 + t] = 0u;
        }
        s[r] = c;
        __syncthreads();
        for (int d = 1; d < 256; d <<= 1) {
            unsigned v = (r >= d) ? s[r - d] : 0u;
            __syncthreads();
            s[r] += v;
            __syncthreads();
        }
        unsigned incl = s[r];
        unsigned above = incl - c;       // keys in strictly higher bins
        unsigned rem = first ? (unsigned)TOPKK : remaining[l];
        __syncthreads();
        if (above < rem && rem <= incl) {
            prefix[l] |= ((unsigned)t) << shift;
            remaining[l] = rem - above;
        }
        __syncthreads();
    }
}

// keep every key >= 16-bit bucket floor; NPART sub-counters per level kill
// the returning-atomic chain (round-1: 68us on one cache line)
__global__ void k_compact(const unsigned* keys, const unsigned* prefix,
                          unsigned* cnt, unsigned long long* cand) {
    unsigned i = blockIdx.x * blockDim.x + threadIdx.x;
    if (i >= NTOT) return;
    unsigned loc; int l = find_level(i, loc);
    unsigned k = keys[i];
    if (k >= prefix[l]) {            // prefix low 16 bits are zero
        unsigned part = blockIdx.x & (NPART - 1);
        unsigned slot = atomicAdd(&cnt[l * NPART + part], 1u);
        if (slot < PART_CAP)
            cand[((size_t)(l * NPART + part)) * PART_CAP + slot] =
                ((unsigned long long)k << 32) | (unsigned)(~loc);
    }
}

__global__ __launch_bounds__(1024) void k_sort_emit(Ptrs p, const unsigned* cnt,
                                                    const unsigned long long* cand,
                                                    float* out) {
    const float MAXD = 4.135166556742356f;   // log(1000/16)
    int l = blockIdx.x;
    int t = threadIdx.x;
    __shared__ unsigned long long buf[CAND_TOT];
    __shared__ float4 sbox[TOPKK];
    __shared__ unsigned sidx[TOPKK];
    __shared__ unsigned offs[NPART + 1];
    __shared__ unsigned pcnt[NPART];

    if (t < NPART) {
        unsigned c = cnt[l * NPART + t];
        pcnt[t] = (c > PART_CAP) ? PART_CAP : c;
    }
    for (int i = t; i < CAND_TOT; i += 1024) buf[i] = 0ULL;
    __syncthreads();
    if (t == 0) {
        unsigned o = 0;
        for (int pp = 0; pp < NPART; pp++) { offs[pp] = o; o += pcnt[pp]; }
        offs[NPART] = o;                       // total (<= 16*PART_CAP)
    }
    __syncthreads();
    {   // wave w copies part w (16 waves of 64 lanes)
        int wv = t >> 6, ln = t & 63;
        unsigned c = pcnt[wv], o = offs[wv];
        for (unsigned e = ln; e < c; e += 64) {
            unsigned dst = o + e;
            if (dst < CAND_TOT)
                buf[dst] = cand[((size_t)(l * NPART + wv)) * PART_CAP + e];
        }
    }
    __syncthreads();

    // bitonic sort, descending composite = key desc then index asc
    for (unsigned k = 2; k <= CAND_TOT; k <<= 1) {
        for (unsigned j = k >> 1; j > 0; j >>= 1) {
            for (unsigned i = t; i < CAND_TOT; i += 1024) {
                unsigned x = i ^ j;
                if (x > i) {
                    unsigned long long a = buf[i], b = buf[x];
                    bool desc = ((i & k) == 0);
                    if (desc ? (a < b) : (a > b)) { buf[i] = b; buf[x] = a; }
                }
            }
            __syncthreads();
        }
    }

    // decode boxes for the 1000 winners
    if (t < TOPKK) {
        unsigned idx = ~((unsigned)(buf[t] & 0xFFFFFFFFull));
        sidx[t] = idx;
        float4 a = ((const float4*)p.anc[l])[idx];
        float4 d = ((const float4*)p.reg[l])[(size_t)idx * 2];   // first 4 of 8
        float w = a.z - a.x, h = a.w - a.y;
        float cx = a.x + 0.5f * w, cy = a.y + 0.5f * h;
        float pcx = cx + d.x * w, pcy = cy + d.y * h;
        float pw = w * expf(fminf(d.z, MAXD));
        float ph = h * expf(fminf(d.w, MAXD));
        sbox[t] = make_float4(pcx - 0.5f * pw, pcy - 0.5f * ph,
                              pcx + 0.5f * pw, pcy + 0.5f * ph);
    }
    __syncthreads();

    const float* cp = p.cls[l];
    for (int o = t; o < TOPKK * NCLS; o += 1024) {
        int j = o >> 4, c = o & 15;
        float sc = cp[(size_t)sidx[j] * NCLS + c];
        sc = 1.0f / (1.0f + expf(-sc));
        float4 b = sbox[j];
        float* q = out + (size_t)((l * TOPKK + j) * NCLS + c) * 6;
        q[0] = b.x; q[1] = b.y; q[2] = b.z; q[3] = b.w;
        q[4] = sc;  q[5] = (float)(c + 1);
    }
}

extern "C" void kernel_launch(void* const* d_in, const int* in_sizes, int n_in,
                              void* d_out, int out_size, void* d_ws, size_t ws_size,
                              hipStream_t stream) {
    Ptrs p;
    for (int l = 0; l < NLEV; l++) {
        p.anc[l] = (const float*)d_in[3 * l + 0];
        p.cls[l] = (const float*)d_in[3 * l + 1];
        p.reg[l] = (const float*)d_in[3 * l + 2];
    }
    char* w = (char*)d_ws;
    // layout (bytes):
    //   keys      : 0 .. 3142656                (785664 u32)
    //   hist      : 3142656 .. +81920           (NPART*5*256 u32 partials)
    //   prefix    : 3224576 .. +32              (5 u32, padded)
    //   remaining : 3224608 .. +32
    //   cnt       : 3224640 .. +320             (5*NPART u32)
    //   cand      : 3224960 .. +327680          (5*NPART*PART_CAP u64)
    unsigned* keys      = (unsigned*)w;
    unsigned* hist      = (unsigned*)(w + 3142656);
    unsigned* prefix    = (unsigned*)(w + 3224576);
    unsigned* remaining = (unsigned*)(w + 3224608);
    unsigned* cnt       = (unsigned*)(w + 3224640);
    unsigned long long* cand = (unsigned long long*)(w + 3224960);

    float* out = (float*)d_out;
    int nb = (NTOT + 255) / 256;

    // zero hist + prefix + remaining + cnt in one async memset (graph-safe)
    (void)hipMemsetAsync(w + 3142656, 0, 81920 + 32 + 32 + 320, stream);
    k_keys_hist<<<nb, 256, 0, stream>>>(p, keys, hist);
    k_select<<<1, 256, 0, stream>>>(hist, prefix, remaining, 24, 1);
    k_hist2<<<nb, 256, 0, stream>>>(keys, prefix, hist);
    k_select<<<1, 256, 0, stream>>>(hist, prefix, remaining, 16, 0);
    k_compact<<<nb, 256, 0, stream>>>(keys, prefix, cnt, cand);
    k_sort_emit<<<NLEV, 1024, 0, stream>>>(p, cnt, cand, out);
}